// Round 3
// baseline (124.699 us; speedup 1.0000x reference)
//
#include <hip/hip_runtime.h>

// Pipelined depthwise 4x4 FIR blur, pad (2,2)/(2,2), NCHW fp32.
// x: [16,256,128,128] -> out: [16,256,129,129]
//
// Block = one image. 4 compute chunks of 32 output rows. LDS = 3-slot ring
// (slot = 32 input rows = 16 KB). Stage chunk j = input rows 32j-2..32j+29
// (OOB rows clamp-loaded as dummies, zero-substituted at compute).
// Counted vmcnt keeps the next stage's global_load_lds in flight across
// barriers (never vmcnt(0) in the loop). Col 126..128 leftover folded into
// g==31 lanes (their xv already holds input cols 120..127; 128/129 are pad).

__global__ __launch_bounds__(256) void blur_fir_pipe(
    const float* __restrict__ x,
    const float* __restrict__ kern,
    float* __restrict__ out)
{
    __shared__ __align__(16) float lds[3 * 32 * 128];   // 48 KB ring

    const int tid  = threadIdx.x;
    const int wv   = tid >> 6;
    const int lane = tid & 63;
    const int c    = tid >> 5;      // row subchunk 0..7 (4 rows each)
    const int g    = tid & 31;      // col group: out cols 4g-2 .. 4g+1
    const bool lv  = (g >= 1);

    const float* __restrict__ xi = x + (size_t)blockIdx.x * (128 * 128);
    float* __restrict__ oi = out + (size_t)blockIdx.x * (129 * 129);

    float w[4][4];
#pragma unroll
    for (int p = 0; p < 4; ++p)
#pragma unroll
        for (int q = 0; q < 4; ++q)
            w[p][q] = kern[4 * p + q];

    // ---- stage chunk J (rows 32J-2 .. 32J+29) into ring slot J%3 ----
    // 16 KB = 16 x 1KB global_load_lds; exactly 4 per wave (vmcnt-exact).
#define STAGE(J) do {                                                        \
        const int slot_ = (J) % 3;                                           \
        _Pragma("unroll")                                                    \
        for (int i_ = 0; i_ < 4; ++i_) {                                     \
            const int q_ = (wv << 2) + i_;                                   \
            int r_ = 32 * (J) - 2 + 2 * q_;                                  \
            r_ = r_ < 0 ? 0 : (r_ > 126 ? 126 : r_);   /* clamp = dummy */   \
            const float* src_ = xi + (size_t)r_ * 128 + (lane << 2);         \
            const float* dst_ = &lds[slot_ * 4096 + q_ * 256];               \
            __builtin_amdgcn_global_load_lds(                                \
                (const __attribute__((address_space(1))) unsigned int*)src_, \
                (__attribute__((address_space(3))) unsigned int*)dst_,       \
                16, 0, 0);                                                   \
        }                                                                    \
    } while (0)

#define LLOAD(S, KK) do {                                                    \
        const int off_ = 4 * c + (KK);                                       \
        const float* pb_ = ((off_ < 32) ? baseA : (baseB - 4096))            \
                           + off_ * 128 + 4 * g - 4;                         \
        const bool okr_ = ((unsigned)(32 * TT + off_ - 2) < 128u);           \
        float4 a_ = make_float4(0.f, 0.f, 0.f, 0.f);                         \
        float4 b_ = make_float4(0.f, 0.f, 0.f, 0.f);                         \
        if (okr_ && lv) a_ = *(const float4*)pb_;                            \
        if (okr_)       b_ = *(const float4*)(pb_ + 4);                      \
        xv[S][0] = a_.x; xv[S][1] = a_.y; xv[S][2] = a_.z; xv[S][3] = a_.w;  \
        xv[S][4] = b_.x; xv[S][5] = b_.y; xv[S][6] = b_.z; xv[S][7] = b_.w;  \
    } while (0)

#define ACCP(S, P) do {                                                      \
        o0 = fmaf(xv[S][0], w[P][0], o0);                                    \
        o1 = fmaf(xv[S][1], w[P][0], o1);                                    \
        o2 = fmaf(xv[S][2], w[P][0], o2);                                    \
        o3 = fmaf(xv[S][3], w[P][0], o3);                                    \
        o0 = fmaf(xv[S][1], w[P][1], o0);                                    \
        o1 = fmaf(xv[S][2], w[P][1], o1);                                    \
        o2 = fmaf(xv[S][3], w[P][1], o2);                                    \
        o3 = fmaf(xv[S][4], w[P][1], o3);                                    \
        o0 = fmaf(xv[S][2], w[P][2], o0);                                    \
        o1 = fmaf(xv[S][3], w[P][2], o1);                                    \
        o2 = fmaf(xv[S][4], w[P][2], o2);                                    \
        o3 = fmaf(xv[S][5], w[P][2], o3);                                    \
        o0 = fmaf(xv[S][3], w[P][3], o0);                                    \
        o1 = fmaf(xv[S][4], w[P][3], o1);                                    \
        o2 = fmaf(xv[S][5], w[P][3], o2);                                    \
        o3 = fmaf(xv[S][6], w[P][3], o3);                                    \
    } while (0)

#define CS(SA, SB, SC, SD, PO) do {                                          \
        float o0 = 0.f, o1 = 0.f, o2 = 0.f, o3 = 0.f;                        \
        ACCP(SA, 0); ACCP(SB, 1); ACCP(SC, 2); ACCP(SD, 3);                  \
        if (lv) { (PO)[0] = o0; (PO)[1] = o1; }                              \
        (PO)[2] = o2;                                                        \
        (PO)[3] = o3;                                                        \
    } while (0)

    // extra cols 126..128 for g==31 (xv idx 0..7 = input cols 120..127;
    // cols 128,129 are zero pad) -- no extra LDS reads.
#define XROW(S, P) do {                                                      \
        e0 = fmaf(xv[S][4], w[P][0], e0);                                    \
        e0 = fmaf(xv[S][5], w[P][1], e0);                                    \
        e0 = fmaf(xv[S][6], w[P][2], e0);                                    \
        e0 = fmaf(xv[S][7], w[P][3], e0);                                    \
        e1 = fmaf(xv[S][5], w[P][0], e1);                                    \
        e1 = fmaf(xv[S][6], w[P][1], e1);                                    \
        e1 = fmaf(xv[S][7], w[P][2], e1);                                    \
        e2 = fmaf(xv[S][6], w[P][0], e2);                                    \
        e2 = fmaf(xv[S][7], w[P][1], e2);                                    \
    } while (0)

#define CSX(SA, SB, SC, SD, PO) do {                                         \
        float e0 = 0.f, e1 = 0.f, e2 = 0.f;                                  \
        XROW(SA, 0); XROW(SB, 1); XROW(SC, 2); XROW(SD, 3);                  \
        (PO)[4] = e0; (PO)[5] = e1; (PO)[6] = e2;  /* cols 126,127,128 */    \
    } while (0)

#define COMPUTE_CHUNK(T) do {                                                \
        const int TT = (T);                                                  \
        const float* baseA = &lds[(TT % 3) * 4096];                          \
        const float* baseB = &lds[((TT + 1) % 3) * 4096];                    \
        float xv[4][8];                                                      \
        float* po = oi + (size_t)(32 * TT + 4 * c) * 129 + 4 * g - 2;        \
        LLOAD(0, 0); LLOAD(1, 1); LLOAD(2, 2); LLOAD(3, 3);                  \
        CS(0, 1, 2, 3, po); if (g == 31) CSX(0, 1, 2, 3, po);                \
        LLOAD(0, 4); po += 129;                                              \
        CS(1, 2, 3, 0, po); if (g == 31) CSX(1, 2, 3, 0, po);                \
        LLOAD(1, 5); po += 129;                                              \
        CS(2, 3, 0, 1, po); if (g == 31) CSX(2, 3, 0, 1, po);                \
        LLOAD(2, 6); po += 129;                                              \
        CS(3, 0, 1, 2, po); if (g == 31) CSX(3, 0, 1, 2, po);                \
        po += 129;                                                           \
        if (TT == 3 && c == 7) {               /* output row 128 */          \
            LLOAD(3, 7);                                                     \
            CS(0, 1, 2, 3, po); if (g == 31) CSX(0, 1, 2, 3, po);            \
        }                                                                    \
    } while (0)

#define WAITV(NSTR)                                                          \
        asm volatile("s_waitcnt vmcnt(" NSTR ")" ::: "memory");              \
        __builtin_amdgcn_sched_barrier(0)

    // ---- pipeline ----
    // per-wave VMEM order: [s0:4][s1:4] [s2:4] W(4) | st0:28 [s3:4] W(32) |
    //                      st1:28 [s4:4] W(32) | st2:28 W(28) | st3
    STAGE(0);
    STAGE(1);

    STAGE(2);
    WAITV("4");                      // stages 0,1 retired; stage 2 in flight
    __builtin_amdgcn_s_barrier();
    COMPUTE_CHUNK(0);
    __builtin_amdgcn_s_barrier();    // WAR: slot 0 about to be re-staged

    STAGE(3);
    WAITV("32");                     // stage 2 retired (28 stores + 4 loads younger)
    __builtin_amdgcn_s_barrier();
    COMPUTE_CHUNK(1);
    __builtin_amdgcn_s_barrier();

    STAGE(4);
    WAITV("32");                     // stage 3 retired
    __builtin_amdgcn_s_barrier();
    COMPUTE_CHUNK(2);
    __builtin_amdgcn_s_barrier();

    WAITV("28");                     // stage 4 retired (28 stores younger)
    __builtin_amdgcn_s_barrier();
    COMPUTE_CHUNK(3);

#undef STAGE
#undef LLOAD
#undef ACCP
#undef CS
#undef XROW
#undef CSX
#undef COMPUTE_CHUNK
#undef WAITV
}

extern "C" void kernel_launch(void* const* d_in, const int* in_sizes, int n_in,
                              void* d_out, int out_size, void* d_ws, size_t ws_size,
                              hipStream_t stream) {
    const float* x    = (const float*)d_in[0];
    const float* kern = (const float*)d_in[1];
    float* out        = (float*)d_out;

    dim3 grid(4096), block(256);     // one block per image
    hipLaunchKernelGGL(blur_fir_pipe, grid, block, 0, stream, x, kern, out);
}

// Round 4
// 116.029 us; speedup vs baseline: 1.0747x; 1.0747x over previous
//
#include <hip/hip_runtime.h>

// Pipelined depthwise 4x4 FIR blur, pad (2,2)/(2,2), NCHW fp32.
// x: [16,256,128,128] -> out: [16,256,129,129]
//
// Block = one image, 512 threads (8 waves). LDS = 4-slot ring, slot = 16
// input rows (8 KB). Stage chunk J = input rows 16J-2 .. 16J+13 (clamped
// dummy loads at edges, zero-substituted at compute). Exactly ONE
// global_load_lds (1 KB = 2 rows) per wave per stage -> exact per-wave
// vmcnt counting; ring-4 keeps 2 stages in flight across raw s_barriers.
// Compute chunk J: thread = out row 16J+c (c=tid>>5), 4 cols (g=tid&31),
// window rows streamed through one 8-float register window.
// Cols 126..128 folded into g==31 (e0..e2); chunk 8 = row 128 (c==0 only).

#define BAR() __builtin_amdgcn_s_barrier()
#define WAITV(NSTR) do {                                                     \
        asm volatile("s_waitcnt vmcnt(" NSTR ")" ::: "memory");              \
        __builtin_amdgcn_sched_barrier(0);                                   \
    } while (0)

__global__ __launch_bounds__(512, 8) void blur_fir_ring4(
    const float* __restrict__ x,
    const float* __restrict__ kern,
    float* __restrict__ out)
{
    __shared__ __align__(16) float lds[4 * 16 * 128];   // 32 KB ring

    const int tid  = threadIdx.x;
    const int wv   = tid >> 6;       // wave 0..7
    const int lane = tid & 63;
    const int c    = tid >> 5;       // row-in-chunk 0..15
    const int g    = tid & 31;       // col group: out cols 4g-2 .. 4g+1
    const bool lv  = (g >= 1);

    const float* __restrict__ xi = x + (size_t)blockIdx.x * (128 * 128);
    float* __restrict__ oi = out + (size_t)blockIdx.x * (129 * 129);

    float w[4][4];
#pragma unroll
    for (int p = 0; p < 4; ++p)
#pragma unroll
        for (int q = 0; q < 4; ++q)
            w[p][q] = kern[4 * p + q];

    // ---- stage chunk J: input rows 16J-2 .. 16J+13 into slot J&3 ----
    // wave wv loads row pair (16J-2+2wv, +1) = 1 KB contiguous, clamped.
#define STAGE(J) do {                                                        \
        int p0_ = 16 * (J) - 2 + 2 * wv;                                     \
        p0_ = p0_ < 0 ? 0 : (p0_ > 126 ? 126 : p0_);   /* clamp = dummy */   \
        const float* src_ = xi + (size_t)p0_ * 128 + (lane << 2);            \
        const float* dst_ = &lds[((J) & 3) * 2048 + wv * 256];               \
        __builtin_amdgcn_global_load_lds(                                    \
            (const __attribute__((address_space(1))) unsigned int*)src_,     \
            (__attribute__((address_space(3))) unsigned int*)dst_,           \
            16, 0, 0);                                                       \
    } while (0)

    // ---- compute chunk J: out row 16J+c, cols 4g-2..4g+1 (+126..128) ----
    // window input rows 16J+c-2+p, p=0..3; slot-row k = c+p (k>=16 -> next
    // slot); zero-substitute rows outside [0,127].
#define COMPUTE(J) do {                                                      \
        float o0 = 0.f, o1 = 0.f, o2 = 0.f, o3 = 0.f;                        \
        float e0 = 0.f, e1 = 0.f, e2 = 0.f;                                  \
        _Pragma("unroll")                                                    \
        for (int p = 0; p < 4; ++p) {                                        \
            const int  k_   = c + p;                                         \
            const bool okr_ = ((unsigned)(16 * (J) - 2 + k_)) < 128u;        \
            const float* pb_ = ((k_ < 16)                                    \
                ? &lds[((J) & 3) * 2048 + k_ * 128]                          \
                : &lds[(((J) + 1) & 3) * 2048 + (k_ - 16) * 128])            \
                + 4 * g - 4;                                                 \
            float4 a_ = make_float4(0.f, 0.f, 0.f, 0.f);                     \
            float4 b_ = make_float4(0.f, 0.f, 0.f, 0.f);                     \
            if (okr_ && lv) a_ = *(const float4*)pb_;                        \
            if (okr_)       b_ = *(const float4*)(pb_ + 4);                  \
            o0 = fmaf(a_.x, w[p][0], o0);                                    \
            o1 = fmaf(a_.y, w[p][0], o1);                                    \
            o2 = fmaf(a_.z, w[p][0], o2);                                    \
            o3 = fmaf(a_.w, w[p][0], o3);                                    \
            o0 = fmaf(a_.y, w[p][1], o0);                                    \
            o1 = fmaf(a_.z, w[p][1], o1);                                    \
            o2 = fmaf(a_.w, w[p][1], o2);                                    \
            o3 = fmaf(b_.x, w[p][1], o3);                                    \
            o0 = fmaf(a_.z, w[p][2], o0);                                    \
            o1 = fmaf(a_.w, w[p][2], o1);                                    \
            o2 = fmaf(b_.x, w[p][2], o2);                                    \
            o3 = fmaf(b_.y, w[p][2], o3);                                    \
            o0 = fmaf(a_.w, w[p][3], o0);                                    \
            o1 = fmaf(b_.x, w[p][3], o1);                                    \
            o2 = fmaf(b_.y, w[p][3], o2);                                    \
            o3 = fmaf(b_.z, w[p][3], o3);                                    \
            /* cols 126..128 (g==31): window cols 124..127 = b_.x..b_.w */   \
            e0 = fmaf(b_.x, w[p][0], e0);                                    \
            e0 = fmaf(b_.y, w[p][1], e0);                                    \
            e0 = fmaf(b_.z, w[p][2], e0);                                    \
            e0 = fmaf(b_.w, w[p][3], e0);                                    \
            e1 = fmaf(b_.y, w[p][0], e1);                                    \
            e1 = fmaf(b_.z, w[p][1], e1);                                    \
            e1 = fmaf(b_.w, w[p][2], e1);                                    \
            e2 = fmaf(b_.z, w[p][0], e2);                                    \
            e2 = fmaf(b_.w, w[p][1], e2);                                    \
        }                                                                    \
        float* po_ = oi + (size_t)(16 * (J) + c) * 129 + 4 * g - 2;          \
        if (lv) { po_[0] = o0; po_[1] = o1; }                                \
        po_[2] = o2;                                                         \
        po_[3] = o3;                                                         \
        if (g == 31) { po_[4] = e0; po_[5] = e1; po_[6] = e2; }              \
    } while (0)
    // per-wave VMEM per COMPUTE: 7 stores (every wave has g==0 and g==31)

    // ---- pipeline: need stage J and J+1 retired before COMPUTE(J). ----
    // Tail-counted waits = #VMEM issued after the required stage.
    STAGE(0); STAGE(1); STAGE(2); STAGE(3);

    WAITV("2");  BAR(); COMPUTE(0); BAR(); STAGE(4);
    WAITV("9");  BAR(); COMPUTE(1); BAR(); STAGE(5);
    WAITV("16"); BAR(); COMPUTE(2); BAR(); STAGE(6);
    WAITV("16"); BAR(); COMPUTE(3); BAR(); STAGE(7);
    WAITV("16"); BAR(); COMPUTE(4); BAR(); STAGE(8);
    WAITV("16"); BAR(); COMPUTE(5); BAR();
    WAITV("15"); BAR(); COMPUTE(6); BAR();
    WAITV("14"); BAR(); COMPUTE(7); BAR();

    // chunk 8 = output row 128 only (c==0): window rows 126..129, all in
    // stage-8 slot (k = p < 4); rows 128,129 zero-substituted via okr.
    if (c == 0) COMPUTE(8);

#undef STAGE
#undef COMPUTE
}

extern "C" void kernel_launch(void* const* d_in, const int* in_sizes, int n_in,
                              void* d_out, int out_size, void* d_ws, size_t ws_size,
                              hipStream_t stream) {
    const float* x    = (const float*)d_in[0];
    const float* kern = (const float*)d_in[1];
    float* out        = (float*)d_out;

    dim3 grid(4096), block(512);     // one block per image, 8 waves
    hipLaunchKernelGGL(blur_fir_ring4, grid, block, 0, stream, x, kern, out);
}